// Round 1
// baseline (749.787 us; speedup 1.0000x reference)
//
#include <hip/hip_runtime.h>

// PureLSTM: B=4096, T=512, I=32, H=16, fp32.
// One wave64 per batch element; lane g in [0,64) owns gate row g (4H=64 rows).
// Weights live in per-lane registers; x[b][t][:] is wave-uniform (uniform-address
// float4 loads, double-buffered); h broadcast via v_readlane each step.

constexpr int BATCH = 4096;
constexpr int SEQ   = 512;
constexpr int ISZ   = 32;
constexpr int HSZ   = 16;

__device__ __forceinline__ float readlane_f(float v, int l) {
  return __int_as_float(__builtin_amdgcn_readlane(__float_as_int(v), l));
}
__device__ __forceinline__ float shfl64_f(float v, int src) {
  return __int_as_float(__builtin_amdgcn_ds_bpermute(src << 2, __float_as_int(v)));
}
__device__ __forceinline__ float fast_rcp(float x) { return __builtin_amdgcn_rcpf(x); }
__device__ __forceinline__ float sigf(float z) { return fast_rcp(1.f + __expf(-z)); }
__device__ __forceinline__ float tanh_fast(float z) {
  // tanh(z) = 2*sigmoid(2z) - 1 ; inf-safe: exp(-2z)->inf => rcp->0 => -1
  return fmaf(2.f, fast_rcp(1.f + __expf(-2.f * z)), -1.f);
}

#define LOADX(buf, tt)                                                        \
  do {                                                                        \
    const float4* p_ = reinterpret_cast<const float4*>(xb + (tt) * ISZ);      \
    _Pragma("unroll") for (int q_ = 0; q_ < 8; ++q_) (buf)[q_] = p_[q_];      \
  } while (0)

#define STEP(buf)                                                             \
  do {                                                                        \
    float a0 = bsum, a1 = 0.f, a2 = 0.f, a3 = 0.f;                            \
    _Pragma("unroll") for (int q_ = 0; q_ < 8; ++q_) {                        \
      a0 = fmaf(w[4 * q_ + 0], (buf)[q_].x, a0);                              \
      a1 = fmaf(w[4 * q_ + 1], (buf)[q_].y, a1);                              \
      a2 = fmaf(w[4 * q_ + 2], (buf)[q_].z, a2);                              \
      a3 = fmaf(w[4 * q_ + 3], (buf)[q_].w, a3);                              \
    }                                                                         \
    _Pragma("unroll") for (int k_ = 0; k_ < HSZ; k_ += 4) {                   \
      a0 = fmaf(wh[k_ + 0], hs[k_ + 0], a0);                                  \
      a1 = fmaf(wh[k_ + 1], hs[k_ + 1], a1);                                  \
      a2 = fmaf(wh[k_ + 2], hs[k_ + 2], a2);                                  \
      a3 = fmaf(wh[k_ + 3], hs[k_ + 3], a3);                                  \
    }                                                                         \
    const float acc = (a0 + a1) + (a2 + a3);                                  \
    const float pI = shfl64_f(acc, j);                                        \
    const float pF = shfl64_f(acc, j + 16);                                   \
    const float pG = shfl64_f(acc, j + 32);                                   \
    const float pO = shfl64_f(acc, j + 48);                                   \
    const float ig = sigf(pI);                                                \
    const float fg = sigf(pF);                                                \
    const float gg = tanh_fast(pG);                                           \
    const float og = sigf(pO);                                                \
    c = fmaf(fg, c, ig * gg);                                                 \
    const float hn = og * tanh_fast(c);                                       \
    _Pragma("unroll") for (int k_ = 0; k_ < HSZ; ++k_)                        \
        hs[k_] = readlane_f(hn, k_);                                          \
  } while (0)

__global__ __launch_bounds__(256) void lstm_fused(
    const float* __restrict__ x, const float* __restrict__ Wih,
    const float* __restrict__ Whh, const float* __restrict__ bih,
    const float* __restrict__ bhh, const float* __restrict__ fcw,
    const float* __restrict__ fcb, float* __restrict__ out) {
  const int lane = threadIdx.x & 63;
  const int wid  = __builtin_amdgcn_readfirstlane(threadIdx.x >> 6);
  const int b    = blockIdx.x * 4 + wid;
  const int g    = lane;       // gate row 0..63  (order: i[0:16) f[16:32) g[32:48) o[48:64))
  const int j    = lane & 15;  // hidden unit this lane finalizes

  // ---- per-lane weights in registers ----
  float w[ISZ];
#pragma unroll
  for (int i = 0; i < ISZ; i += 4) {
    const float4 v = *reinterpret_cast<const float4*>(Wih + g * ISZ + i);
    w[i] = v.x; w[i + 1] = v.y; w[i + 2] = v.z; w[i + 3] = v.w;
  }
  float wh[HSZ];
#pragma unroll
  for (int i = 0; i < HSZ; i += 4) {
    const float4 v = *reinterpret_cast<const float4*>(Whh + g * HSZ + i);
    wh[i] = v.x; wh[i + 1] = v.y; wh[i + 2] = v.z; wh[i + 3] = v.w;
  }
  const float bsum = bih[g] + bhh[g];

  const float* xb = x + (size_t)b * (SEQ * ISZ);

  float hs[HSZ];  // wave-uniform h (readlane results -> SGPR-resident)
#pragma unroll
  for (int k = 0; k < HSZ; ++k) hs[k] = 0.f;
  float c = 0.f;

  // ---- recurrent loop, 2-step double buffer ----
  float4 bufA[8], bufB[8];
  LOADX(bufA, 0);
  for (int t = 0; t < SEQ; t += 2) {
    LOADX(bufB, t + 1);
    STEP(bufA);
    const int t2 = (t + 2 < SEQ) ? (t + 2) : 0;  // clamp: avoid OOB prefetch on last iter
    LOADX(bufA, t2);
    STEP(bufB);
  }

  // ---- epilogue: out[b] = sigmoid(h . fc_w + fc_b) ----
  float s = fcb[0];
#pragma unroll
  for (int k = 0; k < HSZ; ++k) s = fmaf(hs[k], fcw[k], s);
  if (lane == 0) out[b] = sigf(s);
}

extern "C" void kernel_launch(void* const* d_in, const int* in_sizes, int n_in,
                              void* d_out, int out_size, void* d_ws, size_t ws_size,
                              hipStream_t stream) {
  const float* x   = (const float*)d_in[0];
  const float* Wih = (const float*)d_in[1];
  const float* Whh = (const float*)d_in[2];
  const float* bih = (const float*)d_in[3];
  const float* bhh = (const float*)d_in[4];
  const float* fcw = (const float*)d_in[5];
  const float* fcb = (const float*)d_in[6];
  float* out = (float*)d_out;

  dim3 grid(BATCH / 4);   // 4 waves (4 batch elements) per 256-thread block
  dim3 block(256);
  hipLaunchKernelGGL(lstm_fused, grid, block, 0, stream,
                     x, Wih, Whh, bih, bhh, fcw, fcb, out);
}